// Round 4
// baseline (395.263 us; speedup 1.0000x reference)
//
#include <hip/hip_runtime.h>
#include <hip/hip_bf16.h>

typedef __bf16 bf16x8 __attribute__((ext_vector_type(8)));
typedef __bf16 bf16x4 __attribute__((ext_vector_type(4)));
typedef float  floatx4 __attribute__((ext_vector_type(4)));

enum { EPI_QKV = 0, EPI_EXP = 1, EPI_CTX = 2, EPI_OUT = 3 };

#define MSH 8388608ll  // 8192*1024, Q/K/V plane stride in the fused epilogue

// Async global->LDS, 16 B per lane. LDS dest is wave-uniform base + lane*16.
#define GLOAD16(gp, lp)                                                        \
  __builtin_amdgcn_global_load_lds(                                            \
      (const __attribute__((address_space(1))) void*)(gp),                     \
      (__attribute__((address_space(3))) void*)(lp), 16, 0, 0)

// ---------------------------------------------------------------------------
// 128x128 tile GEMM, BK=64, 512 threads = 8 waves. Wave w owns a 64x32
// sub-tile: rows (w>>2)*64, cols (w&3)*32, as 4x2 MFMA 16x16x32 tiles.
// 32 acc regs/wave (vs 64 for the 4-wave variant) -> higher occupancy,
// which is what hides the K-loop barrier drain (m114).
// A: M x K row-major bf16. B: N x K row-major bf16.
// EPI_QKV : N=3072 fused projection; cols 0-1023 -> Q(+b0), 1024-2047 ->
//           K(+b1) row-major; 2048-3071 -> V(+b2) written TRANSPOSED.
// EPI_EXP : E = exp(mask ? 1e-20 : v*scale) -> bf16; rowsum atomics into Lbuf.
// EPI_CTX : v / Lbuf[row] -> bf16.
// EPI_OUT : v + b0 -> fp32.
// ---------------------------------------------------------------------------
template <int EPI>
__global__ __launch_bounds__(512) void gemm128(
    const __bf16* __restrict__ Ag, const __bf16* __restrict__ Bg,
    const float* __restrict__ b0, const float* __restrict__ b1,
    const float* __restrict__ b2, void* __restrict__ Cv,
    const int* __restrict__ mask, float* __restrict__ Lbuf,
    int Kd, int lda, int ldb, int ldc,
    long long sA, long long sB, long long sC, long long sM, float scale) {
  const int bz = blockIdx.z;
  const __bf16* A  = Ag + (size_t)bz * sA;
  const __bf16* Bp = Bg + (size_t)bz * sB;
  const int m0 = blockIdx.y * 128;
  const int n0 = blockIdx.x * 128;

  __shared__ __bf16 As[128 * 64];
  __shared__ __bf16 Bs[128 * 64];

  const int tid  = threadIdx.x;
  const int lane = tid & 63;
  const int w    = tid >> 6;          // 0..7
  const int lo   = lane & 15;
  const int quad = lane >> 4;
  const int lrow  = lane >> 3;        // staging: row within 8-row group
  const int lcol8 = (lane & 7) * 8;   // staging: 8-elem (16 B) column chunk

  floatx4 acc[4][2];
#pragma unroll
  for (int mt = 0; mt < 4; mt++)
#pragma unroll
    for (int nt = 0; nt < 2; nt++) acc[mt][nt] = (floatx4){0.f, 0.f, 0.f, 0.f};

  // Wave w stages rows [w*16, w*16+16) of both tiles: 2 insts x 8 rows each.
  const __bf16* aptr = A + (size_t)(m0 + w * 16 + lrow) * lda + lcol8;
  const __bf16* bptr = Bp + (size_t)(n0 + w * 16 + lrow) * ldb + lcol8;
  __bf16* asl = As + (w * 16) * 64;   // wave-uniform LDS bases
  __bf16* bsl = Bs + (w * 16) * 64;

  const int mrow = (w >> 2) * 64;     // compute-side row base
  const int ncol = (w & 3) * 32;      // compute-side col base

  for (int kk = 0; kk < Kd; kk += 64) {
    GLOAD16(aptr + kk, asl);
    GLOAD16(aptr + (size_t)8 * lda + kk, asl + 8 * 64);
    GLOAD16(bptr + kk, bsl);
    GLOAD16(bptr + (size_t)8 * ldb + kk, bsl + 8 * 64);
    __syncthreads();
#pragma unroll
    for (int kq = 0; kq < 2; kq++) {
      bf16x8 af[4], bfq[2];
#pragma unroll
      for (int mt = 0; mt < 4; mt++)
        af[mt] = *(const bf16x8*)&As[(mrow + mt * 16 + lo) * 64 + kq * 32 + quad * 8];
#pragma unroll
      for (int nt = 0; nt < 2; nt++)
        bfq[nt] = *(const bf16x8*)&Bs[(ncol + nt * 16 + lo) * 64 + kq * 32 + quad * 8];
#pragma unroll
      for (int mt = 0; mt < 4; mt++)
#pragma unroll
        for (int nt = 0; nt < 2; nt++)
          acc[mt][nt] = __builtin_amdgcn_mfma_f32_16x16x32_bf16(af[mt], bfq[nt], acc[mt][nt], 0, 0, 0);
    }
    __syncthreads();
  }

  // Epilogue. C/D layout (m89): col = lane&15, row = (lane>>4)*4 + r.
  if (EPI == EPI_QKV) {
    const int which = n0 >> 10;  // 0=Q 1=K 2=V (block-uniform; 128 | 1024)
    const float* bp = (which == 0) ? b0 : (which == 1) ? b1 : b2;
#pragma unroll
    for (int mt = 0; mt < 4; mt++) {
      const int gmb = m0 + mrow + mt * 16 + quad * 4;
#pragma unroll
      for (int nt = 0; nt < 2; nt++) {
        const int gn  = n0 + ncol + nt * 16 + lo;
        const int gnl = gn & 1023;
        const float bv_ = bp[gnl];
        if (which == 2) {
          // V transposed: Vt[bb][gnl][sm..sm+3], packed 8 B.
          const int bb = gmb >> 11, sm = gmb & 2047;
          bf16x4 pk;
#pragma unroll
          for (int r = 0; r < 4; r++) pk[r] = (__bf16)(acc[mt][nt][r] + bv_);
          *(bf16x4*)((__bf16*)Cv + 2 * MSH + ((size_t)bb * 1024 + gnl) * 2048 + sm) = pk;
        } else {
#pragma unroll
          for (int r = 0; r < 4; r++)
            ((__bf16*)Cv)[(size_t)which * MSH + (size_t)(gmb + r) * 1024 + gnl] =
                (__bf16)(acc[mt][nt][r] + bv_);
        }
      }
    }
  } else if (EPI == EPI_EXP) {
#pragma unroll
    for (int mt = 0; mt < 4; mt++) {
      const int gmb = m0 + mrow + mt * 16 + quad * 4;
#pragma unroll
      for (int r = 0; r < 4; r++) {
        const int gm = gmb + r;
        float rowpart = 0.f;
#pragma unroll
        for (int nt = 0; nt < 2; nt++) {
          const int gn = n0 + ncol + nt * 16 + lo;
          float s = acc[mt][nt][r] * scale;
          if (mask[(size_t)bz * sM + (size_t)gm * ldc + gn] != 0) s = 1e-20f;
          const float e = __expf(s);
          rowpart += e;
          ((__bf16*)Cv)[(size_t)bz * sC + (size_t)gm * ldc + gn] = (__bf16)e;
        }
        rowpart += __shfl_xor(rowpart, 1);
        rowpart += __shfl_xor(rowpart, 2);
        rowpart += __shfl_xor(rowpart, 4);
        rowpart += __shfl_xor(rowpart, 8);
        if (lo == 0) atomicAdd(&Lbuf[(size_t)bz * 2048 + gm], rowpart);
      }
    }
  } else {
#pragma unroll
    for (int mt = 0; mt < 4; mt++) {
      const int gmb = m0 + mrow + mt * 16 + quad * 4;
#pragma unroll
      for (int nt = 0; nt < 2; nt++) {
        const int gn = n0 + ncol + nt * 16 + lo;
#pragma unroll
        for (int r = 0; r < 4; r++) {
          const int gm = gmb + r;
          const size_t ci = (size_t)bz * sC + (size_t)gm * ldc + gn;
          if (EPI == EPI_CTX) {
            const float inv = 1.0f / Lbuf[(size_t)bz * 2048 + gm];
            ((__bf16*)Cv)[ci] = (__bf16)(acc[mt][nt][r] * inv);
          } else {  // EPI_OUT
            ((float*)Cv)[ci] = acc[mt][nt][r] + b0[gn];
          }
        }
      }
    }
  }
}

// Convert fp32 X -> bf16, 4 elems/thread.
__global__ __launch_bounds__(256) void cvtx_k(const float* __restrict__ X,
                                              __bf16* __restrict__ Xb) {
  const size_t i = (size_t)blockIdx.x * 256 + threadIdx.x;
  const float4 v = ((const float4*)X)[i];
  bf16x4 o;
  o[0] = (__bf16)v.x; o[1] = (__bf16)v.y; o[2] = (__bf16)v.z; o[3] = (__bf16)v.w;
  ((bf16x4*)Xb)[i] = o;
}

// Transpose+convert the 4 weight matrices (1024x1024 fp32 K x N) into bf16
// N x K at Wt + z*1M.
__global__ __launch_bounds__(256) void wtrans_k(
    const float* __restrict__ Wq, const float* __restrict__ Wk,
    const float* __restrict__ Wv, const float* __restrict__ Wo,
    __bf16* __restrict__ Wt) {
  const int z = blockIdx.z;
  const float* W = (z == 0) ? Wq : (z == 1) ? Wk : (z == 2) ? Wv : Wo;
  __bf16* D = Wt + (size_t)z * 1024 * 1024;
  __shared__ float T[64][65];
  const int r0 = blockIdx.y * 64, c0 = blockIdx.x * 64;
#pragma unroll
  for (int i = 0; i < 16; i++) {
    const int e = i * 256 + threadIdx.x;
    const int r = e >> 6, c = e & 63;
    T[r][c] = W[(size_t)(r0 + r) * 1024 + c0 + c];
  }
  __syncthreads();
#pragma unroll
  for (int i = 0; i < 16; i++) {
    const int e = i * 256 + threadIdx.x;
    const int rr = e >> 6, cc = e & 63;
    D[(size_t)(c0 + rr) * 1024 + r0 + cc] = (__bf16)T[cc][rr];
  }
}

extern "C" void kernel_launch(void* const* d_in, const int* in_sizes, int n_in,
                              void* d_out, int out_size, void* d_ws, size_t ws_size,
                              hipStream_t stream) {
  (void)in_sizes; (void)n_in; (void)out_size; (void)ws_size;
  const int B = 4, S = 2048, H = 1024;
  const int MS = B * S;  // 8192

  const float* X   = (const float*)d_in[0];
  const int*   msk = (const int*)d_in[1];
  const float* Wq  = (const float*)d_in[2];
  const float* bq  = (const float*)d_in[3];
  const float* Wk  = (const float*)d_in[4];
  const float* bk  = (const float*)d_in[5];
  const float* Wv  = (const float*)d_in[6];
  const float* bv  = (const float*)d_in[7];
  const float* Wo  = (const float*)d_in[8];
  const float* bo  = (const float*)d_in[9];
  float* out = (float*)d_out;

  // Workspace (~109.2 MB):
  //   Xb[16.8M] Wt[8.4M] Qb[16.8M] Kb[16.8M] Vt[16.8M] E[33.6M bf16] L[32K]
  //   Cx (ctx, 16.8M) aliases Xb (dead after QKV projection).
  char* ws = (char*)d_ws;
  __bf16* Xb = (__bf16*)ws;
  __bf16* Wt = Xb + (size_t)MS * H;
  __bf16* Qb = Wt + (size_t)4 * H * H;   // Q,K,Vt contiguous (QKV epilogue)
  __bf16* Kb = Qb + (size_t)MS * H;
  __bf16* Vt = Kb + (size_t)MS * H;
  __bf16* E  = Vt + (size_t)MS * H;
  float*  L  = (float*)(E + (size_t)B * S * S);
  __bf16* Cx = Xb;  // alias

  dim3 blk(512);
  dim3 blk256(256);

  hipMemsetAsync(L, 0, (size_t)B * S * sizeof(float), stream);
  cvtx_k<<<dim3(MS * H / 4 / 256), blk256, 0, stream>>>(X, Xb);
  wtrans_k<<<dim3(16, 16, 4), blk256, 0, stream>>>(Wq, Wk, Wv, Wo, Wt);

  // Fused QKV projection: [8192 x 3072] = Xb @ Wt[0:3072]^T (+biases).
  gemm128<EPI_QKV><<<dim3(3 * H / 128, MS / 128, 1), blk, 0, stream>>>(
      Xb, Wt, bq, bk, bv, Qb, nullptr, nullptr,
      H, H, H, H, 0, 0, 0, 0, 0.f);

  // Scores -> E = exp(mask ? 1e-20 : QK^T/32) bf16, rowsums into L.
  gemm128<EPI_EXP><<<dim3(S / 128, S / 128, B), blk, 0, stream>>>(
      Qb, Kb, nullptr, nullptr, nullptr, E, msk, L,
      H, H, H, S, (long long)S * H, (long long)S * H,
      (long long)S * S, (long long)S * S, 0.03125f);

  // ctx: per batch [2048x1024] = (E @ Vt^T) / L -> bf16.
  gemm128<EPI_CTX><<<dim3(H / 128, S / 128, B), blk, 0, stream>>>(
      E, Vt, nullptr, nullptr, nullptr, Cx, nullptr, L,
      S, S, S, H, (long long)S * S, (long long)H * S, (long long)S * H, 0, 0.f);

  // out: [8192x1024] = Cx @ Wo^T + bo -> fp32.
  gemm128<EPI_OUT><<<dim3(H / 128, MS / 128, 1), blk, 0, stream>>>(
      Cx, Wt + (size_t)3 * H * H, bo, nullptr, nullptr, out, nullptr, nullptr,
      H, H, H, H, 0, 0, 0, 0, 0.f);
}

// Round 5
// 388.354 us; speedup vs baseline: 1.0178x; 1.0178x over previous
//
#include <hip/hip_runtime.h>
#include <hip/hip_bf16.h>

typedef __bf16 bf16x8 __attribute__((ext_vector_type(8)));
typedef __bf16 bf16x4 __attribute__((ext_vector_type(4)));
typedef float  floatx4 __attribute__((ext_vector_type(4)));

enum { EPI_QKV = 0, EPI_EXP = 1, EPI_CTX = 2, EPI_OUT = 3 };

#define MSH 8388608ll  // 8192*1024, Q/K/V plane stride in the fused epilogue

// Async global->LDS, 16 B per lane. LDS dest is wave-uniform base + lane*16.
#define GLOAD16(gp, lp)                                                        \
  __builtin_amdgcn_global_load_lds(                                            \
      (const __attribute__((address_space(1))) void*)(gp),                     \
      (__attribute__((address_space(3))) void*)(lp), 16, 0, 0)

// ---------------------------------------------------------------------------
// 128x128 tile GEMM, BK=64, 256 threads = 4 waves; wave w owns the 64x64
// quadrant (rows (w>>1)*64, cols (w&1)*64) as 4x4 MFMA 16x16x32 tiles.
// (8-wave/64x32 variant measured WORSE: 1.5x LDS reads per MFMA — round 4.)
// A: M x K row-major bf16. B: N x K row-major bf16.
// EPI_QKV : blockIdx.y<16 -> mask pack blocks (int32 mask -> bitmask Pk),
//           overlapped under the compute-bound GEMM. Otherwise N=3072 fused
//           projection; cols 0-1023 -> Q(+b0), 1024-2047 -> K(+b1) row-major,
//           2048-3071 -> V(+b2) written TRANSPOSED.
// EPI_EXP : E = exp(maskbit ? 1e-20 : v*scale) -> bf16; rowsums atomic to L.
// EPI_CTX : v / Lbuf[row] -> bf16.
// EPI_OUT : v + b0 -> fp32.
// ---------------------------------------------------------------------------
template <int EPI>
__global__ __launch_bounds__(256) void gemm128(
    const __bf16* __restrict__ Ag, const __bf16* __restrict__ Bg,
    const float* __restrict__ b0, const float* __restrict__ b1,
    const float* __restrict__ b2, void* __restrict__ Cv,
    const int* __restrict__ mask, unsigned* __restrict__ Pk,
    float* __restrict__ Lbuf,
    int Kd, int lda, int ldb, int ldc,
    long long sA, long long sB, long long sC, float scale) {
  const int tid  = threadIdx.x;

  if constexpr (EPI == EPI_QKV) {
    if (blockIdx.y < 16) {
      // Mask pack: 4*2048*2048 ints -> 524288 u32 bit-words.
      const int pb = blockIdx.x + blockIdx.y * 24;  // 0..383
      for (int idx = pb * 256 + tid; idx < 524288; idx += 384 * 256) {
        const int4* m4 = (const int4*)(mask + (size_t)idx * 32);
        unsigned bits = 0;
#pragma unroll
        for (int q = 0; q < 8; q++) {
          int4 v = m4[q];
          bits |= (v.x != 0 ? 1u : 0u) << (q * 4);
          bits |= (v.y != 0 ? 1u : 0u) << (q * 4 + 1);
          bits |= (v.z != 0 ? 1u : 0u) << (q * 4 + 2);
          bits |= (v.w != 0 ? 1u : 0u) << (q * 4 + 3);
        }
        Pk[idx] = bits;
      }
      return;
    }
  }

  const int bz = blockIdx.z;
  const __bf16* A  = Ag + (size_t)bz * sA;
  const __bf16* Bp = Bg + (size_t)bz * sB;
  const int by = (EPI == EPI_QKV) ? ((int)blockIdx.y - 16) : (int)blockIdx.y;
  const int m0 = by * 128;
  const int n0 = blockIdx.x * 128;

  __shared__ __bf16 As[128 * 64];
  __shared__ __bf16 Bs[128 * 64];

  const int lane = tid & 63;
  const int w    = tid >> 6;          // 0..3
  const int lo   = lane & 15;
  const int quad = lane >> 4;
  const int lrow  = lane >> 3;        // staging: row within 8-row group
  const int lcol8 = (lane & 7) * 8;   // staging: 8-elem (16 B) column chunk

  floatx4 acc[4][4];
#pragma unroll
  for (int mt = 0; mt < 4; mt++)
#pragma unroll
    for (int nt = 0; nt < 4; nt++) acc[mt][nt] = (floatx4){0.f, 0.f, 0.f, 0.f};

  // Each wave stages rows [w*32, w*32+32) of both tiles: 4 insts x 8 rows.
  const __bf16* aptr = A + (size_t)(m0 + w * 32 + lrow) * lda + lcol8;
  const __bf16* bptr = Bp + (size_t)(n0 + w * 32 + lrow) * ldb + lcol8;
  __bf16* asl = As + (w * 32) * 64;   // wave-uniform LDS bases
  __bf16* bsl = Bs + (w * 32) * 64;

  for (int kk = 0; kk < Kd; kk += 64) {
#pragma unroll
    for (int i = 0; i < 4; i++) {
      GLOAD16(aptr + (size_t)(i * 8) * lda + kk, asl + i * 8 * 64);
      GLOAD16(bptr + (size_t)(i * 8) * ldb + kk, bsl + i * 8 * 64);
    }
    __syncthreads();
#pragma unroll
    for (int kq = 0; kq < 2; kq++) {
      bf16x8 af[4], bfq[4];
#pragma unroll
      for (int mt = 0; mt < 4; mt++)
        af[mt] = *(const bf16x8*)&As[((w >> 1) * 64 + mt * 16 + lo) * 64 + kq * 32 + quad * 8];
#pragma unroll
      for (int nt = 0; nt < 4; nt++)
        bfq[nt] = *(const bf16x8*)&Bs[((w & 1) * 64 + nt * 16 + lo) * 64 + kq * 32 + quad * 8];
#pragma unroll
      for (int mt = 0; mt < 4; mt++)
#pragma unroll
        for (int nt = 0; nt < 4; nt++)
          acc[mt][nt] = __builtin_amdgcn_mfma_f32_16x16x32_bf16(af[mt], bfq[nt], acc[mt][nt], 0, 0, 0);
    }
    __syncthreads();
  }

  // Epilogue. C/D layout (m89): col = lane&15, row = (lane>>4)*4 + r.
  if (EPI == EPI_QKV) {
    const int which = n0 >> 10;  // 0=Q 1=K 2=V (block-uniform; 128 | 1024)
    const float* bp = (which == 0) ? b0 : (which == 1) ? b1 : b2;
#pragma unroll
    for (int mt = 0; mt < 4; mt++) {
      const int gmb = m0 + (w >> 1) * 64 + mt * 16 + quad * 4;
#pragma unroll
      for (int nt = 0; nt < 4; nt++) {
        const int gn  = n0 + (w & 1) * 64 + nt * 16 + lo;
        const int gnl = gn & 1023;
        const float bv_ = bp[gnl];
        if (which == 2) {
          // V transposed: Vt[bb][gnl][sm..sm+3], packed 8 B.
          const int bb = gmb >> 11, sm = gmb & 2047;
          bf16x4 pk;
#pragma unroll
          for (int r = 0; r < 4; r++) pk[r] = (__bf16)(acc[mt][nt][r] + bv_);
          *(bf16x4*)((__bf16*)Cv + 2 * MSH + ((size_t)bb * 1024 + gnl) * 2048 + sm) = pk;
        } else {
#pragma unroll
          for (int r = 0; r < 4; r++)
            ((__bf16*)Cv)[(size_t)which * MSH + (size_t)(gmb + r) * 1024 + gnl] =
                (__bf16)(acc[mt][nt][r] + bv_);
        }
      }
    }
  } else if (EPI == EPI_EXP) {
    const unsigned* Pb = Pk + (size_t)bz * 2048 * 64;
#pragma unroll
    for (int mt = 0; mt < 4; mt++) {
      const int gmb = m0 + (w >> 1) * 64 + mt * 16 + quad * 4;
#pragma unroll
      for (int r = 0; r < 4; r++) {
        const int gm = gmb + r;
        float rowpart = 0.f;
#pragma unroll
        for (int nt = 0; nt < 4; nt++) {
          const int gn = n0 + (w & 1) * 64 + nt * 16 + lo;
          const unsigned wd = Pb[(size_t)gm * 64 + (gn >> 5)];
          float s = acc[mt][nt][r] * scale;
          if ((wd >> (gn & 31)) & 1u) s = 1e-20f;
          const float e = __expf(s);
          rowpart += e;
          ((__bf16*)Cv)[(size_t)bz * sC + (size_t)gm * ldc + gn] = (__bf16)e;
        }
        rowpart += __shfl_xor(rowpart, 1);
        rowpart += __shfl_xor(rowpart, 2);
        rowpart += __shfl_xor(rowpart, 4);
        rowpart += __shfl_xor(rowpart, 8);
        if (lo == 0) atomicAdd(&Lbuf[(size_t)bz * 2048 + gm], rowpart);
      }
    }
  } else {
#pragma unroll
    for (int mt = 0; mt < 4; mt++) {
      const int gmb = m0 + (w >> 1) * 64 + mt * 16 + quad * 4;
#pragma unroll
      for (int nt = 0; nt < 4; nt++) {
        const int gn = n0 + (w & 1) * 64 + nt * 16 + lo;
#pragma unroll
        for (int r = 0; r < 4; r++) {
          const int gm = gmb + r;
          const size_t ci = (size_t)bz * sC + (size_t)gm * ldc + gn;
          if (EPI == EPI_CTX) {
            const float inv = 1.0f / Lbuf[(size_t)bz * 2048 + gm];
            ((__bf16*)Cv)[ci] = (__bf16)(acc[mt][nt][r] * inv);
          } else {  // EPI_OUT
            ((float*)Cv)[ci] = acc[mt][nt][r] + b0[gn];
          }
        }
      }
    }
  }
}

// Prep kernel, grid (16,16,5):
//   z=0..3 : transpose+convert W[z] (1024x1024 fp32 K x N) -> bf16 N x K.
//   z=4    : convert fp32 X -> bf16 (grid-stride), and zero L (first 32 blocks).
__global__ __launch_bounds__(256) void prep_k(
    const float* __restrict__ X, __bf16* __restrict__ Xb,
    const float* __restrict__ Wq, const float* __restrict__ Wk,
    const float* __restrict__ Wv, const float* __restrict__ Wo,
    __bf16* __restrict__ Wt, float* __restrict__ L) {
  const int z = blockIdx.z;
  const int tid = threadIdx.x;
  if (z == 4) {
    const int bid = blockIdx.y * 16 + blockIdx.x;  // 0..255
    if (bid < 32) L[bid * 256 + tid] = 0.f;
#pragma unroll
    for (int k = 0; k < 32; k++) {
      const size_t i = (size_t)(bid * 256 + tid) + (size_t)k * 65536;
      const float4 v = ((const float4*)X)[i];
      bf16x4 o;
      o[0] = (__bf16)v.x; o[1] = (__bf16)v.y; o[2] = (__bf16)v.z; o[3] = (__bf16)v.w;
      ((bf16x4*)Xb)[i] = o;
    }
    return;
  }
  const float* W = (z == 0) ? Wq : (z == 1) ? Wk : (z == 2) ? Wv : Wo;
  __bf16* D = Wt + (size_t)z * 1024 * 1024;
  __shared__ float T[64][65];
  const int r0 = blockIdx.y * 64, c0 = blockIdx.x * 64;
#pragma unroll
  for (int i = 0; i < 16; i++) {
    const int e = i * 256 + tid;
    const int r = e >> 6, c = e & 63;
    T[r][c] = W[(size_t)(r0 + r) * 1024 + c0 + c];
  }
  __syncthreads();
#pragma unroll
  for (int i = 0; i < 16; i++) {
    const int e = i * 256 + tid;
    const int rr = e >> 6, cc = e & 63;
    D[(size_t)(c0 + rr) * 1024 + r0 + cc] = (__bf16)T[cc][rr];
  }
}

extern "C" void kernel_launch(void* const* d_in, const int* in_sizes, int n_in,
                              void* d_out, int out_size, void* d_ws, size_t ws_size,
                              hipStream_t stream) {
  (void)in_sizes; (void)n_in; (void)out_size; (void)ws_size;
  const int B = 4, S = 2048, H = 1024;
  const int MS = B * S;  // 8192

  const float* X   = (const float*)d_in[0];
  const int*   msk = (const int*)d_in[1];
  const float* Wq  = (const float*)d_in[2];
  const float* bq  = (const float*)d_in[3];
  const float* Wk  = (const float*)d_in[4];
  const float* bk  = (const float*)d_in[5];
  const float* Wv  = (const float*)d_in[6];
  const float* bv  = (const float*)d_in[7];
  const float* Wo  = (const float*)d_in[8];
  const float* bo  = (const float*)d_in[9];
  float* out = (float*)d_out;

  // Workspace (~111.3 MB):
  //   Xb[16.8M] Wt[8.4M] Qb[16.8M] Kb[16.8M] Vt[16.8M] E[33.6M bf16]
  //   L[32K] Pk[2.1M bitmask]
  //   Cx (ctx, 16.8M) aliases Xb (dead after QKV projection).
  char* ws = (char*)d_ws;
  __bf16* Xb = (__bf16*)ws;
  __bf16* Wt = Xb + (size_t)MS * H;
  __bf16* Qb = Wt + (size_t)4 * H * H;   // Q,K,Vt contiguous (QKV epilogue)
  __bf16* Kb = Qb + (size_t)MS * H;
  __bf16* Vt = Kb + (size_t)MS * H;
  __bf16* E  = Vt + (size_t)MS * H;
  float*  L  = (float*)(E + (size_t)B * S * S);
  unsigned* Pk = (unsigned*)(L + (size_t)B * S);
  __bf16* Cx = Xb;  // alias

  dim3 blk(256);

  prep_k<<<dim3(16, 16, 5), blk, 0, stream>>>(X, Xb, Wq, Wk, Wv, Wo, Wt, L);

  // Fused QKV projection [8192 x 3072] = Xb @ Wt[0:3072]^T (+biases),
  // plus mask-pack blocks (y<16) overlapped under the compute-bound GEMM.
  gemm128<EPI_QKV><<<dim3(3 * H / 128, MS / 128 + 16, 1), blk, 0, stream>>>(
      Xb, Wt, bq, bk, bv, Qb, msk, Pk, nullptr,
      H, H, H, H, 0, 0, 0, 0.f);

  // Scores -> E = exp(maskbit ? 1e-20 : QK^T/32) bf16, rowsums into L.
  gemm128<EPI_EXP><<<dim3(S / 128, S / 128, B), blk, 0, stream>>>(
      Qb, Kb, nullptr, nullptr, nullptr, E, nullptr, Pk, L,
      H, H, H, S, (long long)S * H, (long long)S * H, (long long)S * S, 0.03125f);

  // ctx: per batch [2048x1024] = (E @ Vt^T) / L -> bf16.
  gemm128<EPI_CTX><<<dim3(H / 128, S / 128, B), blk, 0, stream>>>(
      E, Vt, nullptr, nullptr, nullptr, Cx, nullptr, nullptr, L,
      S, S, S, H, (long long)S * S, (long long)H * S, (long long)S * H, 0.f);

  // out: [8192x1024] = Cx @ Wo^T + bo -> fp32.
  gemm128<EPI_OUT><<<dim3(H / 128, MS / 128, 1), blk, 0, stream>>>(
      Cx, Wt + (size_t)3 * H * H, bo, nullptr, nullptr, out, nullptr, nullptr, nullptr,
      H, H, H, H, 0, 0, 0, 0.f);
}

// Round 6
// 378.419 us; speedup vs baseline: 1.0445x; 1.0263x over previous
//
#include <hip/hip_runtime.h>
#include <hip/hip_bf16.h>

typedef __bf16 bf16x8 __attribute__((ext_vector_type(8)));
typedef __bf16 bf16x4 __attribute__((ext_vector_type(4)));
typedef float  floatx4 __attribute__((ext_vector_type(4)));

#define SH  2097152ll  // per-batch plane: 2048*1024
#define MSH 8388608ll  // full Q/K/V plane: 8192*1024
#define SS  4194304ll  // per-batch score plane: 2048*2048

// Async global->LDS, 16 B per lane. LDS dest is wave-uniform base + lane*16.
#define GLOAD16(gp, lp)                                                        \
  __builtin_amdgcn_global_load_lds(                                            \
      (const __attribute__((address_space(1))) void*)(gp),                     \
      (__attribute__((address_space(3))) void*)(lp), 16, 0, 0)

// ---------------------------------------------------------------------------
// Shared 128x128xBK64 GEMM core: 256 threads = 4 waves, wave w owns the 64x64
// quadrant (rows (w>>1)*64, cols (w&1)*64) as 4x4 16x16x32 bf16 MFMA tiles.
// A: M x K row-major bf16, B: N x K row-major bf16. (Round-3 config — the
// 8-wave 64x32 variant measured WORSE: 1.5x LDS reads per MFMA, round 4.)
// ---------------------------------------------------------------------------
__device__ __forceinline__ void gemm_core(
    const __bf16* __restrict__ A, const __bf16* __restrict__ B,
    __bf16* As, __bf16* Bs, floatx4 (&acc)[4][4],
    int m0, int n0, int Kd, int lda, int ldb, int tid) {
  const int lane = tid & 63;
  const int w    = tid >> 6;
  const int lo   = lane & 15;
  const int quad = lane >> 4;
  const int lrow  = lane >> 3;
  const int lcol8 = (lane & 7) * 8;

  const __bf16* aptr = A + (size_t)(m0 + w * 32 + lrow) * lda + lcol8;
  const __bf16* bptr = B + (size_t)(n0 + w * 32 + lrow) * ldb + lcol8;
  __bf16* asl = As + (w * 32) * 64;
  __bf16* bsl = Bs + (w * 32) * 64;

  for (int kk = 0; kk < Kd; kk += 64) {
#pragma unroll
    for (int i = 0; i < 4; i++) {
      GLOAD16(aptr + (size_t)(i * 8) * lda + kk, asl + i * 8 * 64);
      GLOAD16(bptr + (size_t)(i * 8) * ldb + kk, bsl + i * 8 * 64);
    }
    __syncthreads();
#pragma unroll
    for (int kq = 0; kq < 2; kq++) {
      bf16x8 af[4], bfq[4];
#pragma unroll
      for (int mt = 0; mt < 4; mt++)
        af[mt] = *(const bf16x8*)&As[((w >> 1) * 64 + mt * 16 + lo) * 64 + kq * 32 + quad * 8];
#pragma unroll
      for (int nt = 0; nt < 4; nt++)
        bfq[nt] = *(const bf16x8*)&Bs[((w & 1) * 64 + nt * 16 + lo) * 64 + kq * 32 + quad * 8];
#pragma unroll
      for (int mt = 0; mt < 4; mt++)
#pragma unroll
        for (int nt = 0; nt < 4; nt++)
          acc[mt][nt] = __builtin_amdgcn_mfma_f32_16x16x32_bf16(af[mt], bfq[nt], acc[mt][nt], 0, 0, 0);
    }
    __syncthreads();
  }
}

#define GEMM_PRE()                                                             \
  __shared__ __bf16 As[128 * 64];                                              \
  __shared__ __bf16 Bs[128 * 64];                                              \
  const int tid = threadIdx.x;                                                 \
  floatx4 acc[4][4];                                                           \
  _Pragma("unroll") for (int mt = 0; mt < 4; mt++)                             \
      _Pragma("unroll") for (int nt = 0; nt < 4; nt++)                         \
          acc[mt][nt] = (floatx4){0.f, 0.f, 0.f, 0.f};                         \
  const int lane = tid & 63, w = tid >> 6, lo = lane & 15, quad = lane >> 4;   \
  (void)lo; (void)quad;

// QKV projection: [8192 x 3072] = Xb @ Wt[0:3072]^T (+bias). grid (24, 64).
// Epilogue: C/D layout (m89): col = lane&15, row = (lane>>4)*4 + r.
__global__ __launch_bounds__(256) void qkv_k(
    const __bf16* __restrict__ Xb, const __bf16* __restrict__ Wt,
    const float* __restrict__ bq, const float* __restrict__ bk,
    const float* __restrict__ bv, __bf16* __restrict__ QKV) {
  GEMM_PRE();
  const int m0 = blockIdx.y * 128, n0 = blockIdx.x * 128;
  gemm_core(Xb, Wt, As, Bs, acc, m0, n0, 1024, 1024, 1024, tid);
  const int which = n0 >> 10;  // 0=Q 1=K 2=V (block-uniform)
  const float* bp = (which == 0) ? bq : (which == 1) ? bk : bv;
#pragma unroll
  for (int mt = 0; mt < 4; mt++) {
    const int gmb = m0 + (w >> 1) * 64 + mt * 16 + quad * 4;
#pragma unroll
    for (int nt = 0; nt < 4; nt++) {
      const int gnl = (n0 + (w & 1) * 64 + nt * 16 + lo) & 1023;
      const float bv_ = bp[gnl];
#pragma unroll
      for (int r = 0; r < 4; r++)
        QKV[(size_t)which * MSH + (size_t)(gmb + r) * 1024 + gnl] =
            (__bf16)(acc[mt][nt][r] + bv_);
    }
  }
}

// MID: grid (16, 24, 4). by<16 -> scores: E = exp(maskbit ? 1e-20 : QK^T/32)
// (bf16) + rowsum atomics into L. by>=16 -> VWo = V @ Wo, written TRANSPOSED
// (VWoT[e][s], bf16x4-packed along s) for the ctx GEMM's B-operand.
// Both halves share K=1024, lda=ldb=1024 — identical core call.
__global__ __launch_bounds__(256) void mid_k(
    const __bf16* __restrict__ QKV, const __bf16* __restrict__ Wt3,
    __bf16* __restrict__ E, __bf16* __restrict__ VWoT,
    const unsigned* __restrict__ Pk, float* __restrict__ L) {
  GEMM_PRE();
  const int bz = blockIdx.z, by = blockIdx.y, bx = blockIdx.x;
  const bool expp = by < 16;
  const __bf16* A = expp ? QKV + bz * SH : QKV + 2 * MSH + bz * SH;
  const __bf16* B = expp ? QKV + MSH + bz * SH : Wt3;
  const int m0 = (expp ? by : bx) * 128;
  const int n0 = (expp ? bx : (by - 16)) * 128;
  gemm_core(A, B, As, Bs, acc, m0, n0, 1024, 1024, 1024, tid);

  if (expp) {
    const unsigned* Pb = Pk + (size_t)bz * 2048 * 64;
#pragma unroll
    for (int mt = 0; mt < 4; mt++) {
      const int gmb = m0 + (w >> 1) * 64 + mt * 16 + quad * 4;
#pragma unroll
      for (int r = 0; r < 4; r++) {
        const int gm = gmb + r;
        float rowpart = 0.f;
#pragma unroll
        for (int nt = 0; nt < 4; nt++) {
          const int gn = n0 + (w & 1) * 64 + nt * 16 + lo;
          const unsigned wd = Pb[(size_t)gm * 64 + (gn >> 5)];
          float s = acc[mt][nt][r] * 0.03125f;
          if ((wd >> (gn & 31)) & 1u) s = 1e-20f;
          const float e = __expf(s);
          rowpart += e;
          E[(size_t)bz * SS + (size_t)gm * 2048 + gn] = (__bf16)e;
        }
        rowpart += __shfl_xor(rowpart, 1);
        rowpart += __shfl_xor(rowpart, 2);
        rowpart += __shfl_xor(rowpart, 4);
        rowpart += __shfl_xor(rowpart, 8);
        if (lo == 0) atomicAdd(&L[(size_t)bz * 2048 + gm], rowpart);
      }
    }
  } else {
#pragma unroll
    for (int mt = 0; mt < 4; mt++) {
      const int gmb = m0 + (w >> 1) * 64 + mt * 16 + quad * 4;  // s index
#pragma unroll
      for (int nt = 0; nt < 4; nt++) {
        const int gn = n0 + (w & 1) * 64 + nt * 16 + lo;        // e index
        bf16x4 pk;
#pragma unroll
        for (int r = 0; r < 4; r++) pk[r] = (__bf16)acc[mt][nt][r];
        *(bf16x4*)(VWoT + (size_t)bz * SH + (size_t)gn * 2048 + gmb) = pk;
      }
    }
  }
}

// CTX/OUT fused: out = (E @ VWoT^T) / L + bo -> fp32. grid (8, 16, 4).
__global__ __launch_bounds__(256) void ctx_k(
    const __bf16* __restrict__ E, const __bf16* __restrict__ VWoT,
    const float* __restrict__ L, const float* __restrict__ bo,
    float* __restrict__ out) {
  GEMM_PRE();
  const int bz = blockIdx.z;
  const int m0 = blockIdx.y * 128, n0 = blockIdx.x * 128;
  gemm_core(E + (size_t)bz * SS, VWoT + (size_t)bz * SH, As, Bs, acc,
            m0, n0, 2048, 2048, 2048, tid);
#pragma unroll
  for (int mt = 0; mt < 4; mt++) {
    const int gmb = m0 + (w >> 1) * 64 + mt * 16 + quad * 4;
#pragma unroll
    for (int nt = 0; nt < 4; nt++) {
      const int gn = n0 + (w & 1) * 64 + nt * 16 + lo;
      const float bo_ = bo[gn];
#pragma unroll
      for (int r = 0; r < 4; r++) {
        const int gm = gmb + r;
        const float inv = 1.0f / L[(size_t)bz * 2048 + gm];
        out[((size_t)bz * 2048 + gm) * 1024 + gn] = acc[mt][nt][r] * inv + bo_;
      }
    }
  }
}

// Prep, grid (16,16,6):
//   z=0..3 : transpose+convert W[z] (1024x1024 fp32 K x N) -> bf16 N x K.
//   z=4    : convert fp32 X -> bf16; zero L (first 32 blocks).
//   z=5    : pack int32 mask (4*2048*2048) -> bitmask Pk (524288 u32).
__global__ __launch_bounds__(256) void prep_k(
    const float* __restrict__ X, __bf16* __restrict__ Xb,
    const float* __restrict__ Wq, const float* __restrict__ Wk,
    const float* __restrict__ Wv, const float* __restrict__ Wo,
    __bf16* __restrict__ Wt, float* __restrict__ L,
    const int* __restrict__ mask, unsigned* __restrict__ Pk) {
  const int z = blockIdx.z;
  const int tid = threadIdx.x;
  const int bid = blockIdx.y * 16 + blockIdx.x;  // 0..255
  if (z == 4) {
    if (bid < 32) L[bid * 256 + tid] = 0.f;
#pragma unroll
    for (int k = 0; k < 32; k++) {
      const size_t i = (size_t)(bid * 256 + tid) + (size_t)k * 65536;
      const float4 v = ((const float4*)X)[i];
      bf16x4 o;
      o[0] = (__bf16)v.x; o[1] = (__bf16)v.y; o[2] = (__bf16)v.z; o[3] = (__bf16)v.w;
      ((bf16x4*)Xb)[i] = o;
    }
    return;
  }
  if (z == 5) {
#pragma unroll
    for (int k = 0; k < 8; k++) {
      const int idx = bid * 256 + tid + k * 65536;
      const int4* m4 = (const int4*)(mask + (size_t)idx * 32);
      unsigned bits = 0;
#pragma unroll
      for (int q = 0; q < 8; q++) {
        int4 v = m4[q];
        bits |= (v.x != 0 ? 1u : 0u) << (q * 4);
        bits |= (v.y != 0 ? 1u : 0u) << (q * 4 + 1);
        bits |= (v.z != 0 ? 1u : 0u) << (q * 4 + 2);
        bits |= (v.w != 0 ? 1u : 0u) << (q * 4 + 3);
      }
      Pk[idx] = bits;
    }
    return;
  }
  const float* W = (z == 0) ? Wq : (z == 1) ? Wk : (z == 2) ? Wv : Wo;
  __bf16* D = Wt + (size_t)z * 1024 * 1024;
  __shared__ float T[64][65];
  const int r0 = blockIdx.y * 64, c0 = blockIdx.x * 64;
#pragma unroll
  for (int i = 0; i < 16; i++) {
    const int e = i * 256 + tid;
    const int r = e >> 6, c = e & 63;
    T[r][c] = W[(size_t)(r0 + r) * 1024 + c0 + c];
  }
  __syncthreads();
#pragma unroll
  for (int i = 0; i < 16; i++) {
    const int e = i * 256 + tid;
    const int rr = e >> 6, cc = e & 63;
    D[(size_t)(c0 + rr) * 1024 + r0 + cc] = (__bf16)T[cc][rr];
  }
}

extern "C" void kernel_launch(void* const* d_in, const int* in_sizes, int n_in,
                              void* d_out, int out_size, void* d_ws, size_t ws_size,
                              hipStream_t stream) {
  (void)in_sizes; (void)n_in; (void)out_size; (void)ws_size;
  const int H = 1024;
  const long long MS = 8192;

  const float* X   = (const float*)d_in[0];
  const int*   msk = (const int*)d_in[1];
  const float* Wq  = (const float*)d_in[2];
  const float* bq  = (const float*)d_in[3];
  const float* Wk  = (const float*)d_in[4];
  const float* bk  = (const float*)d_in[5];
  const float* Wv  = (const float*)d_in[6];
  const float* bv  = (const float*)d_in[7];
  const float* Wo  = (const float*)d_in[8];
  const float* bo  = (const float*)d_in[9];
  float* out = (float*)d_out;

  // Workspace (~111.3 MB):
  //   Xb[16.8M] Wt[8.4M] QKV[50.3M] E[33.6M bf16] L[32K] Pk[2.1M]
  //   VWoT (16.8M) aliases Xb (dead after QKV projection).
  char* ws = (char*)d_ws;
  __bf16* Xb  = (__bf16*)ws;
  __bf16* Wt  = Xb + (size_t)MS * H;
  __bf16* QKV = Wt + (size_t)4 * H * H;
  __bf16* E   = QKV + (size_t)3 * MS * H;
  float*  L   = (float*)(E + (size_t)4 * SS);
  unsigned* Pk = (unsigned*)(L + 8192);
  __bf16* VWoT = Xb;  // alias

  dim3 blk(256);

  prep_k<<<dim3(16, 16, 6), blk, 0, stream>>>(X, Xb, Wq, Wk, Wv, Wo, Wt, L, msk, Pk);
  qkv_k<<<dim3(24, 64), blk, 0, stream>>>(Xb, Wt, bq, bk, bv, QKV);
  mid_k<<<dim3(16, 24, 4), blk, 0, stream>>>(QKV, Wt + (size_t)3 * H * H, E, VWoT, Pk, L);
  ctx_k<<<dim3(8, 16, 4), blk, 0, stream>>>(E, VWoT, L, bo, out);
}